// Round 2
// baseline (8256.739 us; speedup 1.0000x reference)
//
#include <hip/hip_runtime.h>
#include <hip/hip_bf16.h>

typedef __hip_bfloat16 bf16;

static constexpr int Bb = 512;
static constexpr int Hh = 512;
static constexpr int Ll = 64;
static constexpr int Vv = 1024;
static constexpr int MAXNB = 8;
static constexpr int Tt = 46;          // 2*(N-1)
static constexpr int TB = Tt * Bb;     // 23552, also PAD index
static constexpr int PADID = TB;
static constexpr int NROWS = TB + Bb;  // 24064

__device__ __forceinline__ float b2f(bf16 v) { return __bfloat162float(v); }
__device__ __forceinline__ float sigm(float x) { return 1.f / (1.f + __expf(-x)); }

// dtype-adaptive load: F32 ? fp32 tensor : bf16 tensor
template <bool F32>
__device__ __forceinline__ float ldv(const void* p, long i) {
  if (F32) return ((const float*)p)[i];
  return __bfloat162float(((const bf16*)p)[i]);
}

// ---------------------------------------------------------------------------
// dtype probe: scan emb bytes as bf16; exponent==0xFF patterns can only occur
// if the underlying data is fp32 (random mantissa halves). Writes flag=1.
// ---------------------------------------------------------------------------
__global__ void detect_kernel(const unsigned short* __restrict__ embu,
                              int* __restrict__ flag) {
  const long n = (long)Vv * Hh;  // bf16-element count of emb
  int bad = 0;
  for (long i = blockIdx.x * 256 + threadIdx.x; i < n; i += 256L * 64) {
    unsigned short u = embu[i];
    if ((u & 0x7F80u) == 0x7F80u) bad = 1;
  }
  if (bad) atomicOr(flag, 1);
}

// ---------------------------------------------------------------------------
// GRU scan step: 1 batch row per block, 512 threads (1 output col per thread)
// ---------------------------------------------------------------------------
template <bool F32>
__device__ void gru_body(int t, const int* __restrict__ wid,
                         const int* __restrict__ hni, const void* emb,
                         const void* Wz, const void* bz, const void* Wr,
                         const void* br, const void* Ur, const void* Wh,
                         const void* bh, bf16* __restrict__ hbuf) {
  const int k = threadIdx.x;
  const int b = blockIdx.x;

  __shared__ float xs[Hh];
  __shared__ float sh[Hh];
  __shared__ float sg[Hh];
  __shared__ float hn[MAXNB][Hh];
  __shared__ int ids_s[MAXNB];

  if (k < MAXNB) ids_s[k] = hni[((long)t * Bb + b) * MAXNB + k];
  __syncthreads();

  const int w = wid[t * Bb + b];
  xs[k] = ldv<F32>(emb, (long)w * Hh + k);
  float s = 0.f;
#pragma unroll
  for (int j = 0; j < MAXNB; ++j) {
    int id = ids_s[j];  // block-uniform -> no divergence
    if (id != PADID) {
      float hv = b2f(hbuf[(long)id * Hh + k]);
      hn[j][k] = hv;
      s += hv;
    }
  }
  sh[k] = s;
  __syncthreads();

  // z = sigmoid([x, sum_h] @ Wz + bz)
  float zA = ldv<F32>(bz, k);
  for (int i = 0; i < Hh; ++i) zA += xs[i] * ldv<F32>(Wz, (long)i * Hh + k);
  for (int i = 0; i < Hh; ++i) zA += sh[i] * ldv<F32>(Wz, (long)(Hh + i) * Hh + k);

  // pre_r = x @ Wr + br
  float pA = ldv<F32>(br, k);
  for (int i = 0; i < Hh; ++i) pA += xs[i] * ldv<F32>(Wr, (long)i * Hh + k);

  // sum_g = sum_j sigmoid(pre_r + h_j @ Ur) * h_j   (pad rows are exact zeros)
  float gA = 0.f;
  for (int j = 0; j < MAXNB; ++j) {
    if (ids_s[j] != PADID) {
      float aA = pA;
      for (int i = 0; i < Hh; ++i) aA += hn[j][i] * ldv<F32>(Ur, (long)i * Hh + k);
      gA += sigm(aA) * hn[j][k];
    }
  }
  sg[k] = gA;
  __syncthreads();

  // h_tilde = tanh([x, sum_g] @ Wh + bh)
  float hA = ldv<F32>(bh, k);
  for (int i = 0; i < Hh; ++i) hA += xs[i] * ldv<F32>(Wh, (long)i * Hh + k);
  for (int i = 0; i < Hh; ++i) hA += sg[i] * ldv<F32>(Wh, (long)(Hh + i) * Hh + k);

  float z = sigm(zA);
  float h = (1.f - z) * s + z * tanhf(hA);
  hbuf[((long)t * Bb + b) * Hh + k] = __float2bfloat16(h);
}

__global__ __launch_bounds__(512) void gru_step(
    int t, const int* __restrict__ wid, const int* __restrict__ hni,
    const void* emb, const void* Wz, const void* bz, const void* Wr,
    const void* br, const void* Ur, const void* Wh, const void* bh,
    bf16* __restrict__ hbuf, const int* __restrict__ flag) {
  if (*flag)
    gru_body<true>(t, wid, hni, emb, Wz, bz, Wr, br, Ur, Wh, bh, hbuf);
  else
    gru_body<false>(t, wid, hni, emb, Wz, bz, Wr, br, Ur, Wh, bh, hbuf);
}

// ---------------------------------------------------------------------------
// Stop head: rows = [emb[w] | sum(hbuf[oni]) | mol_vec] (24064 x 1088)
// s = relu(row @ U + bU) @ Us + bs ; BCE loss + accuracy
// ---------------------------------------------------------------------------
template <bool F32>
__device__ void stop_body(const void* mol_vec, const int* __restrict__ wid,
                          const int* __restrict__ dirs,
                          const int* __restrict__ oni,
                          const int* __restrict__ root_wid,
                          const int* __restrict__ roni, const void* emb,
                          const void* U, const void* bU, const void* Us,
                          const void* bs, const bf16* __restrict__ hbuf,
                          float* __restrict__ accum) {
  const int tid = threadIdx.x;
  const int i0 = blockIdx.x * 8;
  const int K = 2 * Hh + Ll;  // 1088

  __shared__ float srow[8][2 * Hh + Ll];
  __shared__ float red[8][256];
  __shared__ float fin[16];

  for (int r = 0; r < 8; ++r) {
    int i = i0 + r;
    int w, b;
    const int* ids;
    if (i < TB) { w = wid[i]; b = i % Bb; ids = &oni[(long)i * MAXNB]; }
    else { int j = i - TB; w = root_wid[j]; b = j; ids = &roni[(long)j * MAXNB]; }
    for (int c = tid; c < K; c += 256) {
      float v;
      if (c < Hh) v = ldv<F32>(emb, (long)w * Hh + c);
      else if (c < 2 * Hh) {
        int cc = c - Hh;
        float s = 0.f;
        for (int j = 0; j < MAXNB; ++j) s += b2f(hbuf[(long)ids[j] * Hh + cc]);
        v = s;
      } else v = ldv<F32>(mol_vec, (long)b * Ll + (c - 2 * Hh));
      srow[r][c] = v;
    }
  }
  __syncthreads();

  const int k0 = tid, k1 = tid + 256;
  float acc[8][2] = {};
  for (int kk = 0; kk < K; ++kk) {
    float u0 = ldv<F32>(U, (long)kk * Hh + k0);
    float u1 = ldv<F32>(U, (long)kk * Hh + k1);
#pragma unroll
    for (int r = 0; r < 8; ++r) {
      float a = srow[r][kk];
      acc[r][0] += a * u0; acc[r][1] += a * u1;
    }
  }
  float bU0 = ldv<F32>(bU, k0), bU1 = ldv<F32>(bU, k1);
  float us0 = ldv<F32>(Us, k0), us1 = ldv<F32>(Us, k1);
  __syncthreads();
#pragma unroll
  for (int r = 0; r < 8; ++r)
    red[r][tid] = fmaxf(acc[r][0] + bU0, 0.f) * us0 + fmaxf(acc[r][1] + bU1, 0.f) * us1;
  __syncthreads();
  for (int off = 128; off; off >>= 1) {
    if (tid < off) {
#pragma unroll
      for (int r = 0; r < 8; ++r) red[r][tid] += red[r][tid + off];
    }
    __syncthreads();
  }
  if (tid < 8) {
    int i = i0 + tid;
    float s = red[tid][0] + ldv<F32>(bs, 0);
    float tgt = (i < TB) ? (float)dirs[i] : 0.f;
    float loss = fmaxf(s, 0.f) - s * tgt + log1pf(expf(-fabsf(s)));
    float ok = ((s >= 0.5f) == (tgt > 0.5f)) ? 1.f : 0.f;
    fin[tid] = loss; fin[8 + tid] = ok;
  }
  __syncthreads();
  if (tid == 0) {
    float ls = 0.f, oks = 0.f;
    for (int r = 0; r < 8; ++r) { ls += fin[r]; oks += fin[8 + r]; }
    atomicAdd(&accum[0], ls);
    atomicAdd(&accum[1], oks);
  }
}

__global__ __launch_bounds__(256) void stop_kernel(
    const void* mol_vec, const int* __restrict__ wid,
    const int* __restrict__ dirs, const int* __restrict__ oni,
    const int* __restrict__ root_wid, const int* __restrict__ roni,
    const void* emb, const void* U, const void* bU, const void* Us,
    const void* bs, const bf16* __restrict__ hbuf, float* __restrict__ accum,
    const int* __restrict__ flag) {
  if (*flag)
    stop_body<true>(mol_vec, wid, dirs, oni, root_wid, roni, emb, U, bU, Us, bs, hbuf, accum);
  else
    stop_body<false>(mol_vec, wid, dirs, oni, root_wid, roni, emb, U, bU, Us, bs, hbuf, accum);
}

// ---------------------------------------------------------------------------
// Pred head: hid = relu([pred_h | pred_mv] @ W + bW); logits = hid @ Wo + bo
// then per-row log-softmax CE + argmax, masked sums.
// ---------------------------------------------------------------------------
template <bool F32>
__device__ void pred_body(const void* mol_vec, const int* __restrict__ y_wid,
                          const int* __restrict__ dirs,
                          const int* __restrict__ root_wid, const void* W,
                          const void* bW, const void* Wo, const void* bo,
                          const bf16* __restrict__ hbuf,
                          float* __restrict__ accum) {
  const int tid = threadIdx.x;
  const int i0 = blockIdx.x * 8;
  const int K1 = Hh + Ll;  // 576

  __shared__ float srow[8][Hh + Ll];
  __shared__ float hid[8][Hh];
  __shared__ float rv[256];
  __shared__ int   ri[256];
  __shared__ float sb[2];

  for (int r = 0; r < 8; ++r) {
    int i = i0 + r;
    int b = (i < Bb) ? i : (i - Bb) % Bb;
    for (int c = tid; c < K1; c += 256) {
      float v;
      if (c < Hh) v = (i < Bb) ? 0.f : b2f(hbuf[(long)(i - Bb) * Hh + c]);
      else v = ldv<F32>(mol_vec, (long)b * Ll + (c - Hh));
      srow[r][c] = v;
    }
  }
  __syncthreads();

  const int k0 = tid, k1 = tid + 256;
  float acc[8][2] = {};
  for (int kk = 0; kk < K1; ++kk) {
    float w0 = ldv<F32>(W, (long)kk * Hh + k0);
    float w1 = ldv<F32>(W, (long)kk * Hh + k1);
#pragma unroll
    for (int r = 0; r < 8; ++r) {
      float a = srow[r][kk];
      acc[r][0] += a * w0; acc[r][1] += a * w1;
    }
  }
  float bW0 = ldv<F32>(bW, k0), bW1 = ldv<F32>(bW, k1);
#pragma unroll
  for (int r = 0; r < 8; ++r) {
    hid[r][k0] = fmaxf(acc[r][0] + bW0, 0.f);
    hid[r][k1] = fmaxf(acc[r][1] + bW1, 0.f);
  }
  __syncthreads();

  float lg[8][4] = {};
  for (int kk = 0; kk < Hh; ++kk) {
    float w0 = ldv<F32>(Wo, (long)kk * Vv + tid);
    float w1 = ldv<F32>(Wo, (long)kk * Vv + tid + 256);
    float w2 = ldv<F32>(Wo, (long)kk * Vv + tid + 512);
    float w3 = ldv<F32>(Wo, (long)kk * Vv + tid + 768);
#pragma unroll
    for (int r = 0; r < 8; ++r) {
      float a = hid[r][kk];
      lg[r][0] += a * w0; lg[r][1] += a * w1;
      lg[r][2] += a * w2; lg[r][3] += a * w3;
    }
  }
  float bo0 = ldv<F32>(bo, tid);
  float bo1 = ldv<F32>(bo, tid + 256);
  float bo2 = ldv<F32>(bo, tid + 512);
  float bo3 = ldv<F32>(bo, tid + 768);

  float plloss = 0.f, pnum = 0.f, pmask = 0.f;  // live in thread 0
  for (int r = 0; r < 8; ++r) {
    int i = i0 + r;
    int tgt = (i < Bb) ? root_wid[i] : y_wid[i - Bb];
    float msk = (i < Bb) ? 1.f : (float)dirs[i - Bb];
    float v0 = lg[r][0] + bo0, v1 = lg[r][1] + bo1;
    float v2 = lg[r][2] + bo2, v3 = lg[r][3] + bo3;

    float bm = v0; int bi = tid;
    if (v1 > bm) { bm = v1; bi = tid + 256; }
    if (v2 > bm) { bm = v2; bi = tid + 512; }
    if (v3 > bm) { bm = v3; bi = tid + 768; }
    rv[tid] = bm; ri[tid] = bi;
    if ((tgt & 255) == tid) {
      int cc = tgt >> 8;
      sb[0] = (cc == 0) ? v0 : (cc == 1) ? v1 : (cc == 2) ? v2 : v3;
    }
    __syncthreads();
    for (int off = 128; off; off >>= 1) {
      if (tid < off) {
        float o = rv[tid + off]; int oi = ri[tid + off];
        if (o > rv[tid] || (o == rv[tid] && oi < ri[tid])) { rv[tid] = o; ri[tid] = oi; }
      }
      __syncthreads();
    }
    float m = rv[0];
    int am = ri[0];
    __syncthreads();
    rv[tid] = __expf(v0 - m) + __expf(v1 - m) + __expf(v2 - m) + __expf(v3 - m);
    __syncthreads();
    for (int off = 128; off; off >>= 1) {
      if (tid < off) rv[tid] += rv[tid + off];
      __syncthreads();
    }
    if (tid == 0) {
      float lse = m + __logf(rv[0]);
      float ce = lse - sb[0];
      plloss += ce * msk;
      pnum += (am == tgt) ? msk : 0.f;
      pmask += msk;
    }
    __syncthreads();
  }
  if (tid == 0) {
    atomicAdd(&accum[2], plloss);
    atomicAdd(&accum[3], pnum);
    atomicAdd(&accum[4], pmask);
  }
}

__global__ __launch_bounds__(256) void pred_kernel(
    const void* mol_vec, const int* __restrict__ y_wid,
    const int* __restrict__ dirs, const int* __restrict__ root_wid,
    const void* W, const void* bW, const void* Wo, const void* bo,
    const bf16* __restrict__ hbuf, float* __restrict__ accum,
    const int* __restrict__ flag) {
  if (*flag)
    pred_body<true>(mol_vec, y_wid, dirs, root_wid, W, bW, Wo, bo, hbuf, accum);
  else
    pred_body<false>(mol_vec, y_wid, dirs, root_wid, W, bW, Wo, bo, hbuf, accum);
}

__global__ void finalize_kernel(const float* __restrict__ accum,
                                const int* __restrict__ flag, void* out) {
  if (threadIdx.x == 0 && blockIdx.x == 0) {
    float o0 = accum[2] / (float)Bb;      // pred_loss
    float o1 = accum[0] / (float)Bb;      // stop_loss
    float o2 = accum[3] / accum[4];       // pred_acc
    float o3 = accum[1] / (float)NROWS;   // stop_acc
    if (*flag) {
      float* o = (float*)out;
      o[0] = o0; o[1] = o1; o[2] = o2; o[3] = o3;
    } else {
      bf16* o = (bf16*)out;
      o[0] = __float2bfloat16(o0); o[1] = __float2bfloat16(o1);
      o[2] = __float2bfloat16(o2); o[3] = __float2bfloat16(o3);
    }
  }
}

extern "C" void kernel_launch(void* const* d_in, const int* in_sizes, int n_in,
                              void* d_out, int out_size, void* d_ws, size_t ws_size,
                              hipStream_t stream) {
  const void* mol_vec  = d_in[0];
  const int*  wid      = (const int*)d_in[1];
  const int*  y_wid    = (const int*)d_in[2];
  const int*  dirs     = (const int*)d_in[3];
  const int*  hni      = (const int*)d_in[4];
  const int*  oni      = (const int*)d_in[5];
  const int*  root_wid = (const int*)d_in[6];
  const int*  roni     = (const int*)d_in[7];
  const void* emb      = d_in[8];
  const void* Wz       = d_in[9];
  const void* bz       = d_in[10];
  const void* Wr       = d_in[11];
  const void* br       = d_in[12];
  const void* Ur       = d_in[13];
  const void* Wh       = d_in[14];
  const void* bh       = d_in[15];
  const void* W        = d_in[16];
  const void* bW       = d_in[17];
  const void* U        = d_in[18];
  const void* bU       = d_in[19];
  const void* Wo       = d_in[20];
  const void* bo       = d_in[21];
  const void* Us       = d_in[22];
  const void* bs       = d_in[23];

  // ws layout: [accum: 8 floats][flag: 1 int][pad to 64B][hbuf: (TB+1)*Hh bf16]
  float* accum = (float*)d_ws;
  int*   flag  = (int*)d_ws + 8;
  bf16*  hbuf  = (bf16*)((char*)d_ws + 64);

  hipMemsetAsync(d_ws, 0, 64, stream);                                   // accum+flag
  hipMemsetAsync(hbuf + (long)TB * Hh, 0, Hh * sizeof(bf16), stream);    // PAD row

  detect_kernel<<<64, 256, 0, stream>>>((const unsigned short*)emb, flag);

  for (int t = 0; t < Tt; ++t) {
    gru_step<<<Bb, 512, 0, stream>>>(t, wid, hni, emb, Wz, bz, Wr, br, Ur,
                                     Wh, bh, hbuf, flag);
  }
  stop_kernel<<<NROWS / 8, 256, 0, stream>>>(mol_vec, wid, dirs, oni, root_wid,
                                             roni, emb, U, bU, Us, bs, hbuf,
                                             accum, flag);
  pred_kernel<<<NROWS / 8, 256, 0, stream>>>(mol_vec, y_wid, dirs, root_wid, W,
                                             bW, Wo, bo, hbuf, accum, flag);
  finalize_kernel<<<1, 64, 0, stream>>>(accum, flag, d_out);
}

// Round 6
// 8233.472 us; speedup vs baseline: 1.0028x; 1.0028x over previous
//
#include <hip/hip_runtime.h>
#include <hip/hip_bf16.h>

typedef __hip_bfloat16 bf16;

static constexpr int Bb = 512;
static constexpr int Hh = 512;
static constexpr int Ll = 64;
static constexpr int Vv = 1024;
static constexpr int MAXNB = 8;
static constexpr int Tt = 46;          // 2*(N-1)
static constexpr int TB = Tt * Bb;     // 23552, also PAD index
static constexpr int PADID = TB;
static constexpr int NROWS = TB + Bb;  // 24064

__device__ __forceinline__ float b2f(bf16 v) { return __bfloat162float(v); }
__device__ __forceinline__ float sigm(float x) { return 1.f / (1.f + __expf(-x)); }

// dtype-adaptive load: F32 ? fp32 tensor : bf16 tensor
template <bool F32>
__device__ __forceinline__ float ldv(const void* p, long i) {
  if (F32) return ((const float*)p)[i];
  return __bfloat162float(((const bf16*)p)[i]);
}

// ---------------------------------------------------------------------------
// dtype probe: scan emb bytes as bf16; exponent==0xFF patterns can only occur
// if the underlying data is fp32 (random mantissa halves). Writes flag=1.
// ---------------------------------------------------------------------------
__global__ void detect_kernel(const unsigned short* __restrict__ embu,
                              int* __restrict__ flag) {
  const long n = (long)Vv * Hh;  // bf16-element count of emb
  int bad = 0;
  for (long i = blockIdx.x * 256 + threadIdx.x; i < n; i += 256L * 64) {
    unsigned short u = embu[i];
    if ((u & 0x7F80u) == 0x7F80u) bad = 1;
  }
  if (bad) atomicOr(flag, 1);
}

// ---------------------------------------------------------------------------
// GRU scan step: 1 batch row per block, 512 threads (1 output col per thread)
// ---------------------------------------------------------------------------
template <bool F32>
__device__ void gru_body(int t, const int* __restrict__ wid,
                         const int* __restrict__ hni, const void* emb,
                         const void* Wz, const void* bz, const void* Wr,
                         const void* br, const void* Ur, const void* Wh,
                         const void* bh, bf16* __restrict__ hbuf) {
  const int k = threadIdx.x;
  const int b = blockIdx.x;

  __shared__ float xs[Hh];
  __shared__ float sh[Hh];
  __shared__ float sg[Hh];
  __shared__ float hn[MAXNB][Hh];
  __shared__ int ids_s[MAXNB];

  if (k < MAXNB) ids_s[k] = hni[((long)t * Bb + b) * MAXNB + k];
  __syncthreads();

  const int w = wid[t * Bb + b];
  xs[k] = ldv<F32>(emb, (long)w * Hh + k);
  float s = 0.f;
#pragma unroll
  for (int j = 0; j < MAXNB; ++j) {
    int id = ids_s[j];  // block-uniform -> no divergence
    if (id != PADID) {
      float hv = b2f(hbuf[(long)id * Hh + k]);
      hn[j][k] = hv;
      s += hv;
    }
  }
  sh[k] = s;
  __syncthreads();

  // z = sigmoid([x, sum_h] @ Wz + bz)
  float zA = ldv<F32>(bz, k);
  for (int i = 0; i < Hh; ++i) zA += xs[i] * ldv<F32>(Wz, (long)i * Hh + k);
  for (int i = 0; i < Hh; ++i) zA += sh[i] * ldv<F32>(Wz, (long)(Hh + i) * Hh + k);

  // pre_r = x @ Wr + br
  float pA = ldv<F32>(br, k);
  for (int i = 0; i < Hh; ++i) pA += xs[i] * ldv<F32>(Wr, (long)i * Hh + k);

  // sum_g = sum_j sigmoid(pre_r + h_j @ Ur) * h_j   (pad rows are exact zeros)
  float gA = 0.f;
  for (int j = 0; j < MAXNB; ++j) {
    if (ids_s[j] != PADID) {
      float aA = pA;
      for (int i = 0; i < Hh; ++i) aA += hn[j][i] * ldv<F32>(Ur, (long)i * Hh + k);
      gA += sigm(aA) * hn[j][k];
    }
  }
  sg[k] = gA;
  __syncthreads();

  // h_tilde = tanh([x, sum_g] @ Wh + bh)
  float hA = ldv<F32>(bh, k);
  for (int i = 0; i < Hh; ++i) hA += xs[i] * ldv<F32>(Wh, (long)i * Hh + k);
  for (int i = 0; i < Hh; ++i) hA += sg[i] * ldv<F32>(Wh, (long)(Hh + i) * Hh + k);

  float z = sigm(zA);
  float h = (1.f - z) * s + z * tanhf(hA);
  hbuf[((long)t * Bb + b) * Hh + k] = __float2bfloat16(h);
}

__global__ __launch_bounds__(512) void gru_step(
    int t, const int* __restrict__ wid, const int* __restrict__ hni,
    const void* emb, const void* Wz, const void* bz, const void* Wr,
    const void* br, const void* Ur, const void* Wh, const void* bh,
    bf16* __restrict__ hbuf, const int* __restrict__ flag) {
  if (*flag)
    gru_body<true>(t, wid, hni, emb, Wz, bz, Wr, br, Ur, Wh, bh, hbuf);
  else
    gru_body<false>(t, wid, hni, emb, Wz, bz, Wr, br, Ur, Wh, bh, hbuf);
}

// ---------------------------------------------------------------------------
// Stop head: rows = [emb[w] | sum(hbuf[oni]) | mol_vec] (24064 x 1088)
// s = relu(row @ U + bU) @ Us + bs ; BCE loss + accuracy
// ---------------------------------------------------------------------------
template <bool F32>
__device__ void stop_body(const void* mol_vec, const int* __restrict__ wid,
                          const int* __restrict__ dirs,
                          const int* __restrict__ oni,
                          const int* __restrict__ root_wid,
                          const int* __restrict__ roni, const void* emb,
                          const void* U, const void* bU, const void* Us,
                          const void* bs, const bf16* __restrict__ hbuf,
                          float* __restrict__ accum) {
  const int tid = threadIdx.x;
  const int i0 = blockIdx.x * 8;
  const int K = 2 * Hh + Ll;  // 1088

  __shared__ float srow[8][2 * Hh + Ll];
  __shared__ float red[8][256];
  __shared__ float fin[16];

  for (int r = 0; r < 8; ++r) {
    int i = i0 + r;
    int w, b;
    const int* ids;
    if (i < TB) { w = wid[i]; b = i % Bb; ids = &oni[(long)i * MAXNB]; }
    else { int j = i - TB; w = root_wid[j]; b = j; ids = &roni[(long)j * MAXNB]; }
    for (int c = tid; c < K; c += 256) {
      float v;
      if (c < Hh) v = ldv<F32>(emb, (long)w * Hh + c);
      else if (c < 2 * Hh) {
        int cc = c - Hh;
        float s = 0.f;
        for (int j = 0; j < MAXNB; ++j) s += b2f(hbuf[(long)ids[j] * Hh + cc]);
        v = s;
      } else v = ldv<F32>(mol_vec, (long)b * Ll + (c - 2 * Hh));
      srow[r][c] = v;
    }
  }
  __syncthreads();

  const int k0 = tid, k1 = tid + 256;
  float acc[8][2] = {};
  for (int kk = 0; kk < K; ++kk) {
    float u0 = ldv<F32>(U, (long)kk * Hh + k0);
    float u1 = ldv<F32>(U, (long)kk * Hh + k1);
#pragma unroll
    for (int r = 0; r < 8; ++r) {
      float a = srow[r][kk];
      acc[r][0] += a * u0; acc[r][1] += a * u1;
    }
  }
  float bU0 = ldv<F32>(bU, k0), bU1 = ldv<F32>(bU, k1);
  float us0 = ldv<F32>(Us, k0), us1 = ldv<F32>(Us, k1);
  __syncthreads();
#pragma unroll
  for (int r = 0; r < 8; ++r)
    red[r][tid] = fmaxf(acc[r][0] + bU0, 0.f) * us0 + fmaxf(acc[r][1] + bU1, 0.f) * us1;
  __syncthreads();
  for (int off = 128; off; off >>= 1) {
    if (tid < off) {
#pragma unroll
      for (int r = 0; r < 8; ++r) red[r][tid] += red[r][tid + off];
    }
    __syncthreads();
  }
  if (tid < 8) {
    int i = i0 + tid;
    float s = red[tid][0] + ldv<F32>(bs, 0);
    float tgt = (i < TB) ? (float)dirs[i] : 0.f;
    float loss = fmaxf(s, 0.f) - s * tgt + log1pf(expf(-fabsf(s)));
    float ok = ((s >= 0.5f) == (tgt > 0.5f)) ? 1.f : 0.f;
    fin[tid] = loss; fin[8 + tid] = ok;
  }
  __syncthreads();
  if (tid == 0) {
    float ls = 0.f, oks = 0.f;
    for (int r = 0; r < 8; ++r) { ls += fin[r]; oks += fin[8 + r]; }
    atomicAdd(&accum[0], ls);
    atomicAdd(&accum[1], oks);
  }
}

__global__ __launch_bounds__(256) void stop_kernel(
    const void* mol_vec, const int* __restrict__ wid,
    const int* __restrict__ dirs, const int* __restrict__ oni,
    const int* __restrict__ root_wid, const int* __restrict__ roni,
    const void* emb, const void* U, const void* bU, const void* Us,
    const void* bs, const bf16* __restrict__ hbuf, float* __restrict__ accum,
    const int* __restrict__ flag) {
  if (*flag)
    stop_body<true>(mol_vec, wid, dirs, oni, root_wid, roni, emb, U, bU, Us, bs, hbuf, accum);
  else
    stop_body<false>(mol_vec, wid, dirs, oni, root_wid, roni, emb, U, bU, Us, bs, hbuf, accum);
}

// ---------------------------------------------------------------------------
// Pred head: hid = relu([pred_h | pred_mv] @ W + bW); logits = hid @ Wo + bo
// then per-row log-softmax CE + argmax, masked sums.
// ---------------------------------------------------------------------------
template <bool F32>
__device__ void pred_body(const void* mol_vec, const int* __restrict__ y_wid,
                          const int* __restrict__ dirs,
                          const int* __restrict__ root_wid, const void* W,
                          const void* bW, const void* Wo, const void* bo,
                          const bf16* __restrict__ hbuf,
                          float* __restrict__ accum) {
  const int tid = threadIdx.x;
  const int i0 = blockIdx.x * 8;
  const int K1 = Hh + Ll;  // 576

  __shared__ float srow[8][Hh + Ll];
  __shared__ float hid[8][Hh];
  __shared__ float rv[256];
  __shared__ int   ri[256];
  __shared__ float sb[2];

  for (int r = 0; r < 8; ++r) {
    int i = i0 + r;
    int b = (i < Bb) ? i : (i - Bb) % Bb;
    for (int c = tid; c < K1; c += 256) {
      float v;
      if (c < Hh) v = (i < Bb) ? 0.f : b2f(hbuf[(long)(i - Bb) * Hh + c]);
      else v = ldv<F32>(mol_vec, (long)b * Ll + (c - Hh));
      srow[r][c] = v;
    }
  }
  __syncthreads();

  const int k0 = tid, k1 = tid + 256;
  float acc[8][2] = {};
  for (int kk = 0; kk < K1; ++kk) {
    float w0 = ldv<F32>(W, (long)kk * Hh + k0);
    float w1 = ldv<F32>(W, (long)kk * Hh + k1);
#pragma unroll
    for (int r = 0; r < 8; ++r) {
      float a = srow[r][kk];
      acc[r][0] += a * w0; acc[r][1] += a * w1;
    }
  }
  float bW0 = ldv<F32>(bW, k0), bW1 = ldv<F32>(bW, k1);
#pragma unroll
  for (int r = 0; r < 8; ++r) {
    hid[r][k0] = fmaxf(acc[r][0] + bW0, 0.f);
    hid[r][k1] = fmaxf(acc[r][1] + bW1, 0.f);
  }
  __syncthreads();

  float lg[8][4] = {};
  for (int kk = 0; kk < Hh; ++kk) {
    float w0 = ldv<F32>(Wo, (long)kk * Vv + tid);
    float w1 = ldv<F32>(Wo, (long)kk * Vv + tid + 256);
    float w2 = ldv<F32>(Wo, (long)kk * Vv + tid + 512);
    float w3 = ldv<F32>(Wo, (long)kk * Vv + tid + 768);
#pragma unroll
    for (int r = 0; r < 8; ++r) {
      float a = hid[r][kk];
      lg[r][0] += a * w0; lg[r][1] += a * w1;
      lg[r][2] += a * w2; lg[r][3] += a * w3;
    }
  }
  float bo0 = ldv<F32>(bo, tid);
  float bo1 = ldv<F32>(bo, tid + 256);
  float bo2 = ldv<F32>(bo, tid + 512);
  float bo3 = ldv<F32>(bo, tid + 768);

  float plloss = 0.f, pnum = 0.f, pmask = 0.f;  // live in thread 0
  for (int r = 0; r < 8; ++r) {
    int i = i0 + r;
    int tgt = (i < Bb) ? root_wid[i] : y_wid[i - Bb];
    float msk = (i < Bb) ? 1.f : (float)dirs[i - Bb];
    float v0 = lg[r][0] + bo0, v1 = lg[r][1] + bo1;
    float v2 = lg[r][2] + bo2, v3 = lg[r][3] + bo3;

    float bm = v0; int bi = tid;
    if (v1 > bm) { bm = v1; bi = tid + 256; }
    if (v2 > bm) { bm = v2; bi = tid + 512; }
    if (v3 > bm) { bm = v3; bi = tid + 768; }
    rv[tid] = bm; ri[tid] = bi;
    if ((tgt & 255) == tid) {
      int cc = tgt >> 8;
      sb[0] = (cc == 0) ? v0 : (cc == 1) ? v1 : (cc == 2) ? v2 : v3;
    }
    __syncthreads();
    for (int off = 128; off; off >>= 1) {
      if (tid < off) {
        float o = rv[tid + off]; int oi = ri[tid + off];
        if (o > rv[tid] || (o == rv[tid] && oi < ri[tid])) { rv[tid] = o; ri[tid] = oi; }
      }
      __syncthreads();
    }
    float m = rv[0];
    int am = ri[0];
    __syncthreads();
    rv[tid] = __expf(v0 - m) + __expf(v1 - m) + __expf(v2 - m) + __expf(v3 - m);
    __syncthreads();
    for (int off = 128; off; off >>= 1) {
      if (tid < off) rv[tid] += rv[tid + off];
      __syncthreads();
    }
    if (tid == 0) {
      float lse = m + __logf(rv[0]);
      float ce = lse - sb[0];
      plloss += ce * msk;
      pnum += (am == tgt) ? msk : 0.f;
      pmask += msk;
    }
    __syncthreads();
  }
  if (tid == 0) {
    atomicAdd(&accum[2], plloss);
    atomicAdd(&accum[3], pnum);
    atomicAdd(&accum[4], pmask);
  }
}

__global__ __launch_bounds__(256) void pred_kernel(
    const void* mol_vec, const int* __restrict__ y_wid,
    const int* __restrict__ dirs, const int* __restrict__ root_wid,
    const void* W, const void* bW, const void* Wo, const void* bo,
    const bf16* __restrict__ hbuf, float* __restrict__ accum,
    const int* __restrict__ flag) {
  if (*flag)
    pred_body<true>(mol_vec, y_wid, dirs, root_wid, W, bW, Wo, bo, hbuf, accum);
  else
    pred_body<false>(mol_vec, y_wid, dirs, root_wid, W, bW, Wo, bo, hbuf, accum);
}

__global__ void finalize_kernel(const float* __restrict__ accum,
                                const int* __restrict__ flag, void* out) {
  if (threadIdx.x == 0 && blockIdx.x == 0) {
    float o0 = accum[2] / (float)Bb;      // pred_loss
    float o1 = accum[0] / (float)Bb;      // stop_loss
    float o2 = accum[3] / accum[4];       // pred_acc
    float o3 = accum[1] / (float)NROWS;   // stop_acc
    if (*flag) {
      float* o = (float*)out;
      o[0] = o0; o[1] = o1; o[2] = o2; o[3] = o3;
    } else {
      bf16* o = (bf16*)out;
      o[0] = __float2bfloat16(o0); o[1] = __float2bfloat16(o1);
      o[2] = __float2bfloat16(o2); o[3] = __float2bfloat16(o3);
    }
  }
}

extern "C" void kernel_launch(void* const* d_in, const int* in_sizes, int n_in,
                              void* d_out, int out_size, void* d_ws, size_t ws_size,
                              hipStream_t stream) {
  const void* mol_vec  = d_in[0];
  const int*  wid      = (const int*)d_in[1];
  const int*  y_wid    = (const int*)d_in[2];
  const int*  dirs     = (const int*)d_in[3];
  const int*  hni      = (const int*)d_in[4];
  const int*  oni      = (const int*)d_in[5];
  const int*  root_wid = (const int*)d_in[6];
  const int*  roni     = (const int*)d_in[7];
  const void* emb      = d_in[8];
  const void* Wz       = d_in[9];
  const void* bz       = d_in[10];
  const void* Wr       = d_in[11];
  const void* br       = d_in[12];
  const void* Ur       = d_in[13];
  const void* Wh       = d_in[14];
  const void* bh       = d_in[15];
  const void* W        = d_in[16];
  const void* bW       = d_in[17];
  const void* U        = d_in[18];
  const void* bU       = d_in[19];
  const void* Wo       = d_in[20];
  const void* bo       = d_in[21];
  const void* Us       = d_in[22];
  const void* bs       = d_in[23];

  // ws layout: [accum: 8 floats][flag: 1 int][pad to 64B][hbuf: (TB+1)*Hh bf16]
  float* accum = (float*)d_ws;
  int*   flag  = (int*)d_ws + 8;
  bf16*  hbuf  = (bf16*)((char*)d_ws + 64);

  hipMemsetAsync(d_ws, 0, 64, stream);                                   // accum+flag
  hipMemsetAsync(hbuf + (long)TB * Hh, 0, Hh * sizeof(bf16), stream);    // PAD row

  detect_kernel<<<64, 256, 0, stream>>>((const unsigned short*)emb, flag);

  for (int t = 0; t < Tt; ++t) {
    gru_step<<<Bb, 512, 0, stream>>>(t, wid, hni, emb, Wz, bz, Wr, br, Ur,
                                     Wh, bh, hbuf, flag);
  }
  stop_kernel<<<NROWS / 8, 256, 0, stream>>>(mol_vec, wid, dirs, oni, root_wid,
                                             roni, emb, U, bU, Us, bs, hbuf,
                                             accum, flag);
  pred_kernel<<<NROWS / 8, 256, 0, stream>>>(mol_vec, y_wid, dirs, root_wid, W,
                                             bW, Wo, bo, hbuf, accum, flag);
  finalize_kernel<<<1, 64, 0, stream>>>(accum, flag, d_out);
}

// Round 7
// 5992.490 us; speedup vs baseline: 1.3778x; 1.3740x over previous
//
#include <hip/hip_runtime.h>
#include <hip/hip_bf16.h>

typedef __hip_bfloat16 bf16;

static constexpr int Bb = 512;
static constexpr int Hh = 512;
static constexpr int Ll = 64;
static constexpr int Vv = 1024;
static constexpr int MAXNB = 8;
static constexpr int Tt = 46;          // 2*(N-1)
static constexpr int TB = Tt * Bb;     // 23552, also PAD index
static constexpr int PADID = TB;
static constexpr int NROWS = TB + Bb;  // 24064

__device__ __forceinline__ float b2f(bf16 v) { return __bfloat162float(v); }
__device__ __forceinline__ float sigm(float x) { return 1.f / (1.f + __expf(-x)); }

// dtype-adaptive load: F32 ? fp32 tensor : bf16 tensor
template <bool F32>
__device__ __forceinline__ float ldv(const void* p, long i) {
  if (F32) return ((const float*)p)[i];
  return __bfloat162float(((const bf16*)p)[i]);
}

// ---------------------------------------------------------------------------
// dtype probe: scan emb bytes as bf16; exponent==0xFF patterns can only occur
// if the underlying data is fp32 (random mantissa halves). Writes flag=1.
// ---------------------------------------------------------------------------
__global__ void detect_kernel(const unsigned short* __restrict__ embu,
                              int* __restrict__ flag) {
  const long n = (long)Vv * Hh;  // bf16-element count of emb
  int bad = 0;
  for (long i = blockIdx.x * 256 + threadIdx.x; i < n; i += 256L * 64) {
    unsigned short u = embu[i];
    if ((u & 0x7F80u) == 0x7F80u) bad = 1;
  }
  if (bad) atomicOr(flag, 1);
}

// ---------------------------------------------------------------------------
// sum_g inner: one Ur stream feeding P compacted (row, neighbor) pairs.
// a[] is a compile-time register array; no wasted fma, Ur read exactly once.
// ---------------------------------------------------------------------------
template <bool F32, int P>
__device__ __forceinline__ void sumg(const void* Ur, int k, const float* hnc,
                                     float p0, float p1, const int* rowf,
                                     float& g0, float& g1) {
  float a[P];
#pragma unroll
  for (int p = 0; p < P; ++p) a[p] = rowf[p] ? p1 : p0;
  for (int i = 0; i < Hh; ++i) {
    float uv = ldv<F32>(Ur, (long)i * Hh + k);
#pragma unroll
    for (int p = 0; p < P; ++p) a[p] += hnc[p * Hh + i] * uv;
  }
#pragma unroll
  for (int p = 0; p < P; ++p) {
    float c = sigm(a[p]) * hnc[p * Hh + k];
    if (rowf[p]) g1 += c; else g0 += c;
  }
}

// ---------------------------------------------------------------------------
// GRU scan step: 2 batch rows per block, 512 threads (1 col, 2 rows each).
// Weight streams (Wz/Wr/Ur/Wh) read once per block and shared by both rows.
// ---------------------------------------------------------------------------
template <bool F32>
__device__ void gru_body(int t, const int* wid, const int* hni,
                         const void* emb, const void* Wz, const void* bz,
                         const void* Wr, const void* br, const void* Ur,
                         const void* Wh, const void* bh, bf16* hbuf,
                         float* xs, float* sh, float* sg, float* hnc,
                         int* cid, int* rowf, int* nvs) {
  const int k = threadIdx.x;
  const int b0 = blockIdx.x * 2;

  if (k < 2 * MAXNB)
    cid[k] = hni[((long)t * Bb + b0 + (k >> 3)) * MAXNB + (k & 7)];
  __syncthreads();
  if (k == 0) {
    int n0 = 0; while (n0 < MAXNB && cid[n0] != PADID) ++n0;
    int n1 = 0; while (n1 < MAXNB && cid[MAXNB + n1] != PADID) ++n1;
    // compact row1's ids to follow row0's (write idx <= read idx: safe)
    for (int j = 0; j < n1; ++j) cid[n0 + j] = cid[MAXNB + j];
    for (int p = 0; p < n0 + n1; ++p) rowf[p] = (p >= n0) ? 1 : 0;
    nvs[0] = n0; nvs[1] = n1;
  }
  __syncthreads();
  const int P = nvs[0] + nvs[1];

  const int w0 = wid[t * Bb + b0];
  const int w1 = wid[t * Bb + b0 + 1];
  xs[k]      = ldv<F32>(emb, (long)w0 * Hh + k);
  xs[Hh + k] = ldv<F32>(emb, (long)w1 * Hh + k);

  float s0 = 0.f, s1 = 0.f;
  for (int p = 0; p < P; ++p) {  // block-uniform bound
    float hv = b2f(hbuf[(long)cid[p] * Hh + k]);
    hnc[p * Hh + k] = hv;
    if (rowf[p]) s1 += hv; else s0 += hv;
  }
  sh[k] = s0; sh[Hh + k] = s1;
  __syncthreads();

  // z pre-activation for both rows: bz + x@Wz[:H] + sum_h@Wz[H:]
  float bzk = ldv<F32>(bz, k);
  float z0 = bzk, z1 = bzk;
  for (int i = 0; i < Hh; ++i) {
    float wv = ldv<F32>(Wz, (long)i * Hh + k);
    z0 += xs[i] * wv; z1 += xs[Hh + i] * wv;
  }
  for (int i = 0; i < Hh; ++i) {
    float wv = ldv<F32>(Wz, (long)(Hh + i) * Hh + k);
    z0 += sh[i] * wv; z1 += sh[Hh + i] * wv;
  }

  // pre_r = br + x@Wr
  float brk = ldv<F32>(br, k);
  float p0 = brk, p1 = brk;
  for (int i = 0; i < Hh; ++i) {
    float wv = ldv<F32>(Wr, (long)i * Hh + k);
    p0 += xs[i] * wv; p1 += xs[Hh + i] * wv;
  }

  // sum_g: single Ur stream over all compacted pairs
  float g0 = 0.f, g1 = 0.f;
  switch (P) {
    case 1:  sumg<F32, 1 >(Ur, k, hnc, p0, p1, rowf, g0, g1); break;
    case 2:  sumg<F32, 2 >(Ur, k, hnc, p0, p1, rowf, g0, g1); break;
    case 3:  sumg<F32, 3 >(Ur, k, hnc, p0, p1, rowf, g0, g1); break;
    case 4:  sumg<F32, 4 >(Ur, k, hnc, p0, p1, rowf, g0, g1); break;
    case 5:  sumg<F32, 5 >(Ur, k, hnc, p0, p1, rowf, g0, g1); break;
    case 6:  sumg<F32, 6 >(Ur, k, hnc, p0, p1, rowf, g0, g1); break;
    case 7:  sumg<F32, 7 >(Ur, k, hnc, p0, p1, rowf, g0, g1); break;
    case 8:  sumg<F32, 8 >(Ur, k, hnc, p0, p1, rowf, g0, g1); break;
    case 9:  sumg<F32, 9 >(Ur, k, hnc, p0, p1, rowf, g0, g1); break;
    case 10: sumg<F32, 10>(Ur, k, hnc, p0, p1, rowf, g0, g1); break;
    case 11: sumg<F32, 11>(Ur, k, hnc, p0, p1, rowf, g0, g1); break;
    case 12: sumg<F32, 12>(Ur, k, hnc, p0, p1, rowf, g0, g1); break;
    case 13: sumg<F32, 13>(Ur, k, hnc, p0, p1, rowf, g0, g1); break;
    case 14: sumg<F32, 14>(Ur, k, hnc, p0, p1, rowf, g0, g1); break;
    case 15: sumg<F32, 15>(Ur, k, hnc, p0, p1, rowf, g0, g1); break;
    case 16: sumg<F32, 16>(Ur, k, hnc, p0, p1, rowf, g0, g1); break;
    default: break;  // P==0: no neighbors, sum_g = 0
  }
  sg[k] = g0; sg[Hh + k] = g1;
  __syncthreads();

  // h_tilde = tanh(bh + x@Wh[:H] + sum_g@Wh[H:])
  float bhk = ldv<F32>(bh, k);
  float h0 = bhk, h1 = bhk;
  for (int i = 0; i < Hh; ++i) {
    float wv = ldv<F32>(Wh, (long)i * Hh + k);
    h0 += xs[i] * wv; h1 += xs[Hh + i] * wv;
  }
  for (int i = 0; i < Hh; ++i) {
    float wv = ldv<F32>(Wh, (long)(Hh + i) * Hh + k);
    h0 += sg[i] * wv; h1 += sg[Hh + i] * wv;
  }

  float z;
  z = sigm(z0); float o0 = (1.f - z) * s0 + z * tanhf(h0);
  z = sigm(z1); float o1 = (1.f - z) * s1 + z * tanhf(h1);
  hbuf[((long)t * Bb + b0) * Hh + k]     = __float2bfloat16(o0);
  hbuf[((long)t * Bb + b0 + 1) * Hh + k] = __float2bfloat16(o1);
}

__global__ __launch_bounds__(512) void gru_step(
    int t, const int* __restrict__ wid, const int* __restrict__ hni,
    const void* emb, const void* Wz, const void* bz, const void* Wr,
    const void* br, const void* Ur, const void* Wh, const void* bh,
    bf16* __restrict__ hbuf, const int* __restrict__ flag) {
  __shared__ float xs[2 * Hh];
  __shared__ float sh[2 * Hh];
  __shared__ float sg[2 * Hh];
  __shared__ float hnc[2 * MAXNB * Hh];
  __shared__ int   cid[2 * MAXNB];
  __shared__ int   rowf[2 * MAXNB];
  __shared__ int   nvs[2];
  if (*flag)
    gru_body<true>(t, wid, hni, emb, Wz, bz, Wr, br, Ur, Wh, bh, hbuf,
                   xs, sh, sg, hnc, cid, rowf, nvs);
  else
    gru_body<false>(t, wid, hni, emb, Wz, bz, Wr, br, Ur, Wh, bh, hbuf,
                    xs, sh, sg, hnc, cid, rowf, nvs);
}

// ---------------------------------------------------------------------------
// Stop head: rows = [emb[w] | sum(hbuf[oni]) | mol_vec] (24064 x 1088)
// s = relu(row @ U + bU) @ Us + bs ; BCE loss + accuracy
// ---------------------------------------------------------------------------
template <bool F32>
__device__ void stop_body(const void* mol_vec, const int* wid,
                          const int* dirs, const int* oni,
                          const int* root_wid, const int* roni,
                          const void* emb, const void* U, const void* bU,
                          const void* Us, const void* bs, const bf16* hbuf,
                          float* accum,
                          float (*srow)[2 * Hh + Ll], float (*red)[256],
                          float* fin) {
  const int tid = threadIdx.x;
  const int i0 = blockIdx.x * 8;
  const int K = 2 * Hh + Ll;  // 1088

  for (int r = 0; r < 8; ++r) {
    int i = i0 + r;
    int w, b;
    const int* ids;
    if (i < TB) { w = wid[i]; b = i % Bb; ids = &oni[(long)i * MAXNB]; }
    else { int j = i - TB; w = root_wid[j]; b = j; ids = &roni[(long)j * MAXNB]; }
    for (int c = tid; c < K; c += 256) {
      float v;
      if (c < Hh) v = ldv<F32>(emb, (long)w * Hh + c);
      else if (c < 2 * Hh) {
        int cc = c - Hh;
        float s = 0.f;
        for (int j = 0; j < MAXNB; ++j) s += b2f(hbuf[(long)ids[j] * Hh + cc]);
        v = s;
      } else v = ldv<F32>(mol_vec, (long)b * Ll + (c - 2 * Hh));
      srow[r][c] = v;
    }
  }
  __syncthreads();

  const int k0 = tid, k1 = tid + 256;
  float acc[8][2] = {};
  for (int kk = 0; kk < K; ++kk) {
    float u0 = ldv<F32>(U, (long)kk * Hh + k0);
    float u1 = ldv<F32>(U, (long)kk * Hh + k1);
#pragma unroll
    for (int r = 0; r < 8; ++r) {
      float a = srow[r][kk];
      acc[r][0] += a * u0; acc[r][1] += a * u1;
    }
  }
  float bU0 = ldv<F32>(bU, k0), bU1 = ldv<F32>(bU, k1);
  float us0 = ldv<F32>(Us, k0), us1 = ldv<F32>(Us, k1);
  __syncthreads();
#pragma unroll
  for (int r = 0; r < 8; ++r)
    red[r][tid] = fmaxf(acc[r][0] + bU0, 0.f) * us0 + fmaxf(acc[r][1] + bU1, 0.f) * us1;
  __syncthreads();
  for (int off = 128; off; off >>= 1) {
    if (tid < off) {
#pragma unroll
      for (int r = 0; r < 8; ++r) red[r][tid] += red[r][tid + off];
    }
    __syncthreads();
  }
  if (tid < 8) {
    int i = i0 + tid;
    float s = red[tid][0] + ldv<F32>(bs, 0);
    float tgt = (i < TB) ? (float)dirs[i] : 0.f;
    float loss = fmaxf(s, 0.f) - s * tgt + log1pf(expf(-fabsf(s)));
    float ok = ((s >= 0.5f) == (tgt > 0.5f)) ? 1.f : 0.f;
    fin[tid] = loss; fin[8 + tid] = ok;
  }
  __syncthreads();
  if (tid == 0) {
    float ls = 0.f, oks = 0.f;
    for (int r = 0; r < 8; ++r) { ls += fin[r]; oks += fin[8 + r]; }
    atomicAdd(&accum[0], ls);
    atomicAdd(&accum[1], oks);
  }
}

__global__ __launch_bounds__(256) void stop_kernel(
    const void* mol_vec, const int* __restrict__ wid,
    const int* __restrict__ dirs, const int* __restrict__ oni,
    const int* __restrict__ root_wid, const int* __restrict__ roni,
    const void* emb, const void* U, const void* bU, const void* Us,
    const void* bs, const bf16* __restrict__ hbuf, float* __restrict__ accum,
    const int* __restrict__ flag) {
  __shared__ float srow[8][2 * Hh + Ll];
  __shared__ float red[8][256];
  __shared__ float fin[16];
  if (*flag)
    stop_body<true>(mol_vec, wid, dirs, oni, root_wid, roni, emb, U, bU, Us,
                    bs, hbuf, accum, srow, red, fin);
  else
    stop_body<false>(mol_vec, wid, dirs, oni, root_wid, roni, emb, U, bU, Us,
                     bs, hbuf, accum, srow, red, fin);
}

// ---------------------------------------------------------------------------
// Pred head: hid = relu([pred_h | pred_mv] @ W + bW); logits = hid @ Wo + bo
// then per-row log-softmax CE + argmax, masked sums.
// ---------------------------------------------------------------------------
template <bool F32>
__device__ void pred_body(const void* mol_vec, const int* y_wid,
                          const int* dirs, const int* root_wid, const void* W,
                          const void* bW, const void* Wo, const void* bo,
                          const bf16* hbuf, float* accum,
                          float (*srow)[Hh + Ll], float (*hid)[Hh],
                          float* rv, int* ri, float* sb) {
  const int tid = threadIdx.x;
  const int i0 = blockIdx.x * 8;
  const int K1 = Hh + Ll;  // 576

  for (int r = 0; r < 8; ++r) {
    int i = i0 + r;
    int b = (i < Bb) ? i : (i - Bb) % Bb;
    for (int c = tid; c < K1; c += 256) {
      float v;
      if (c < Hh) v = (i < Bb) ? 0.f : b2f(hbuf[(long)(i - Bb) * Hh + c]);
      else v = ldv<F32>(mol_vec, (long)b * Ll + (c - Hh));
      srow[r][c] = v;
    }
  }
  __syncthreads();

  const int k0 = tid, k1 = tid + 256;
  float acc[8][2] = {};
  for (int kk = 0; kk < K1; ++kk) {
    float w0 = ldv<F32>(W, (long)kk * Hh + k0);
    float w1 = ldv<F32>(W, (long)kk * Hh + k1);
#pragma unroll
    for (int r = 0; r < 8; ++r) {
      float a = srow[r][kk];
      acc[r][0] += a * w0; acc[r][1] += a * w1;
    }
  }
  float bW0 = ldv<F32>(bW, k0), bW1 = ldv<F32>(bW, k1);
#pragma unroll
  for (int r = 0; r < 8; ++r) {
    hid[r][k0] = fmaxf(acc[r][0] + bW0, 0.f);
    hid[r][k1] = fmaxf(acc[r][1] + bW1, 0.f);
  }
  __syncthreads();

  float lg[8][4] = {};
  for (int kk = 0; kk < Hh; ++kk) {
    float w0 = ldv<F32>(Wo, (long)kk * Vv + tid);
    float w1 = ldv<F32>(Wo, (long)kk * Vv + tid + 256);
    float w2 = ldv<F32>(Wo, (long)kk * Vv + tid + 512);
    float w3 = ldv<F32>(Wo, (long)kk * Vv + tid + 768);
#pragma unroll
    for (int r = 0; r < 8; ++r) {
      float a = hid[r][kk];
      lg[r][0] += a * w0; lg[r][1] += a * w1;
      lg[r][2] += a * w2; lg[r][3] += a * w3;
    }
  }
  float bo0 = ldv<F32>(bo, tid);
  float bo1 = ldv<F32>(bo, tid + 256);
  float bo2 = ldv<F32>(bo, tid + 512);
  float bo3 = ldv<F32>(bo, tid + 768);

  float plloss = 0.f, pnum = 0.f, pmask = 0.f;  // live in thread 0
  for (int r = 0; r < 8; ++r) {
    int i = i0 + r;
    int tgt = (i < Bb) ? root_wid[i] : y_wid[i - Bb];
    float msk = (i < Bb) ? 1.f : (float)dirs[i - Bb];
    float v0 = lg[r][0] + bo0, v1 = lg[r][1] + bo1;
    float v2 = lg[r][2] + bo2, v3 = lg[r][3] + bo3;

    float bm = v0; int bi = tid;
    if (v1 > bm) { bm = v1; bi = tid + 256; }
    if (v2 > bm) { bm = v2; bi = tid + 512; }
    if (v3 > bm) { bm = v3; bi = tid + 768; }
    rv[tid] = bm; ri[tid] = bi;
    if ((tgt & 255) == tid) {
      int cc = tgt >> 8;
      sb[0] = (cc == 0) ? v0 : (cc == 1) ? v1 : (cc == 2) ? v2 : v3;
    }
    __syncthreads();
    for (int off = 128; off; off >>= 1) {
      if (tid < off) {
        float o = rv[tid + off]; int oi = ri[tid + off];
        if (o > rv[tid] || (o == rv[tid] && oi < ri[tid])) { rv[tid] = o; ri[tid] = oi; }
      }
      __syncthreads();
    }
    float m = rv[0];
    int am = ri[0];
    __syncthreads();
    rv[tid] = __expf(v0 - m) + __expf(v1 - m) + __expf(v2 - m) + __expf(v3 - m);
    __syncthreads();
    for (int off = 128; off; off >>= 1) {
      if (tid < off) rv[tid] += rv[tid + off];
      __syncthreads();
    }
    if (tid == 0) {
      float lse = m + __logf(rv[0]);
      float ce = lse - sb[0];
      plloss += ce * msk;
      pnum += (am == tgt) ? msk : 0.f;
      pmask += msk;
    }
    __syncthreads();
  }
  if (tid == 0) {
    atomicAdd(&accum[2], plloss);
    atomicAdd(&accum[3], pnum);
    atomicAdd(&accum[4], pmask);
  }
}

__global__ __launch_bounds__(256) void pred_kernel(
    const void* mol_vec, const int* __restrict__ y_wid,
    const int* __restrict__ dirs, const int* __restrict__ root_wid,
    const void* W, const void* bW, const void* Wo, const void* bo,
    const bf16* __restrict__ hbuf, float* __restrict__ accum,
    const int* __restrict__ flag) {
  __shared__ float srow[8][Hh + Ll];
  __shared__ float hid[8][Hh];
  __shared__ float rv[256];
  __shared__ int   ri[256];
  __shared__ float sb[2];
  if (*flag)
    pred_body<true>(mol_vec, y_wid, dirs, root_wid, W, bW, Wo, bo, hbuf,
                    accum, srow, hid, rv, ri, sb);
  else
    pred_body<false>(mol_vec, y_wid, dirs, root_wid, W, bW, Wo, bo, hbuf,
                     accum, srow, hid, rv, ri, sb);
}

__global__ void finalize_kernel(const float* __restrict__ accum,
                                const int* __restrict__ flag, void* out) {
  if (threadIdx.x == 0 && blockIdx.x == 0) {
    float o0 = accum[2] / (float)Bb;      // pred_loss
    float o1 = accum[0] / (float)Bb;      // stop_loss
    float o2 = accum[3] / accum[4];       // pred_acc
    float o3 = accum[1] / (float)NROWS;   // stop_acc
    if (*flag) {
      float* o = (float*)out;
      o[0] = o0; o[1] = o1; o[2] = o2; o[3] = o3;
    } else {
      bf16* o = (bf16*)out;
      o[0] = __float2bfloat16(o0); o[1] = __float2bfloat16(o1);
      o[2] = __float2bfloat16(o2); o[3] = __float2bfloat16(o3);
    }
  }
}

extern "C" void kernel_launch(void* const* d_in, const int* in_sizes, int n_in,
                              void* d_out, int out_size, void* d_ws, size_t ws_size,
                              hipStream_t stream) {
  const void* mol_vec  = d_in[0];
  const int*  wid      = (const int*)d_in[1];
  const int*  y_wid    = (const int*)d_in[2];
  const int*  dirs     = (const int*)d_in[3];
  const int*  hni      = (const int*)d_in[4];
  const int*  oni      = (const int*)d_in[5];
  const int*  root_wid = (const int*)d_in[6];
  const int*  roni     = (const int*)d_in[7];
  const void* emb      = d_in[8];
  const void* Wz       = d_in[9];
  const void* bz       = d_in[10];
  const void* Wr       = d_in[11];
  const void* br       = d_in[12];
  const void* Ur       = d_in[13];
  const void* Wh       = d_in[14];
  const void* bh       = d_in[15];
  const void* W        = d_in[16];
  const void* bW       = d_in[17];
  const void* U        = d_in[18];
  const void* bU       = d_in[19];
  const void* Wo       = d_in[20];
  const void* bo       = d_in[21];
  const void* Us       = d_in[22];
  const void* bs       = d_in[23];

  // ws layout: [accum: 8 floats][flag: 1 int][pad to 64B][hbuf: (TB+1)*Hh bf16]
  float* accum = (float*)d_ws;
  int*   flag  = (int*)d_ws + 8;
  bf16*  hbuf  = (bf16*)((char*)d_ws + 64);

  hipMemsetAsync(d_ws, 0, 64, stream);                                   // accum+flag
  hipMemsetAsync(hbuf + (long)TB * Hh, 0, Hh * sizeof(bf16), stream);    // PAD row

  detect_kernel<<<64, 256, 0, stream>>>((const unsigned short*)emb, flag);

  for (int t = 0; t < Tt; ++t) {
    gru_step<<<Bb / 2, 512, 0, stream>>>(t, wid, hni, emb, Wz, bz, Wr, br, Ur,
                                         Wh, bh, hbuf, flag);
  }
  stop_kernel<<<NROWS / 8, 256, 0, stream>>>(mol_vec, wid, dirs, oni, root_wid,
                                             roni, emb, U, bU, Us, bs, hbuf,
                                             accum, flag);
  pred_kernel<<<NROWS / 8, 256, 0, stream>>>(mol_vec, y_wid, dirs, root_wid, W,
                                             bW, Wo, bo, hbuf, accum, flag);
  finalize_kernel<<<1, 64, 0, stream>>>(accum, flag, d_out);
}

// Round 8
// 3940.152 us; speedup vs baseline: 2.0955x; 1.5209x over previous
//
#include <hip/hip_runtime.h>
#include <hip/hip_bf16.h>

typedef __hip_bfloat16 bf16;

static constexpr int Bb = 512;
static constexpr int Hh = 512;
static constexpr int Ll = 64;
static constexpr int Vv = 1024;
static constexpr int MAXNB = 8;
static constexpr int Tt = 46;          // 2*(N-1)
static constexpr int TB = Tt * Bb;     // 23552, also PAD index
static constexpr int PADID = TB;
static constexpr int NROWS = TB + Bb;  // 24064
static constexpr int XPS = 3 * Hh;     // xproj row stride (bf16 elems)

__device__ __forceinline__ float b2f(bf16 v) { return __bfloat162float(v); }
__device__ __forceinline__ float sigm(float x) { return 1.f / (1.f + __expf(-x)); }

// dtype-adaptive load: F32 ? fp32 tensor : bf16 tensor
template <bool F32>
__device__ __forceinline__ float ldv(const void* p, long i) {
  if (F32) return ((const float*)p)[i];
  return __bfloat162float(((const bf16*)p)[i]);
}

// ---------------------------------------------------------------------------
// dtype probe: scan emb bytes as bf16; exponent==0xFF patterns can only occur
// if the underlying data is fp32 (random mantissa halves). Writes flag=1.
// ---------------------------------------------------------------------------
__global__ void detect_kernel(const unsigned short* __restrict__ embu,
                              int* __restrict__ flag) {
  const long n = (long)Vv * Hh;  // bf16-element count of emb
  int bad = 0;
  for (long i = blockIdx.x * 256 + threadIdx.x; i < n; i += 256L * 64) {
    unsigned short u = embu[i];
    if ((u & 0x7F80u) == 0x7F80u) bad = 1;
  }
  if (bad) atomicOr(flag, 1);
}

// ---------------------------------------------------------------------------
// xproj[v] = [emb[v]@Wz[:H]+bz | emb[v]@Wr+br | emb[v]@Wh[:H]+bh], bf16 out.
// ---------------------------------------------------------------------------
template <bool F32>
__device__ void xproj_body(const void* emb, const void* Wz, const void* bz,
                           const void* Wr, const void* br, const void* Wh,
                           const void* bh, bf16* xproj, float* xe) {
  const int v = blockIdx.x, k = threadIdx.x;
  xe[k] = ldv<F32>(emb, (long)v * Hh + k);
  __syncthreads();
  float z = ldv<F32>(bz, k);
  float r = ldv<F32>(br, k);
  float h = ldv<F32>(bh, k);
  for (int i = 0; i < Hh; ++i) {
    float a = xe[i];
    z += a * ldv<F32>(Wz, (long)i * Hh + k);
    r += a * ldv<F32>(Wr, (long)i * Hh + k);
    h += a * ldv<F32>(Wh, (long)i * Hh + k);
  }
  bf16* xp = xproj + (long)v * XPS;
  xp[k]          = __float2bfloat16(z);
  xp[Hh + k]     = __float2bfloat16(r);
  xp[2 * Hh + k] = __float2bfloat16(h);
}

__global__ __launch_bounds__(512) void xproj_kernel(
    const void* emb, const void* Wz, const void* bz, const void* Wr,
    const void* br, const void* Wh, const void* bh, bf16* xproj,
    const int* __restrict__ flag) {
  __shared__ float xe[Hh];
  if (*flag)
    xproj_body<true>(emb, Wz, bz, Wr, br, Wh, bh, xproj, xe);
  else
    xproj_body<false>(emb, Wz, bz, Wr, br, Wh, bh, xproj, xe);
}

// ---------------------------------------------------------------------------
// sum_g inner: one Ur stream feeding P compacted (row, neighbor) pairs.
// ---------------------------------------------------------------------------
template <bool F32, int P>
__device__ __forceinline__ void sumg(const void* Ur, int k, const float* hnc,
                                     float p0, float p1, const int* rowf,
                                     float& g0, float& g1) {
  float a[P];
#pragma unroll
  for (int p = 0; p < P; ++p) a[p] = rowf[p] ? p1 : p0;
  for (int i = 0; i < Hh; ++i) {
    float uv = ldv<F32>(Ur, (long)i * Hh + k);
#pragma unroll
    for (int p = 0; p < P; ++p) a[p] += hnc[p * Hh + i] * uv;
  }
#pragma unroll
  for (int p = 0; p < P; ++p) {
    float c = sigm(a[p]) * hnc[p * Hh + k];
    if (rowf[p]) g1 += c; else g0 += c;
  }
}

#define SUMG_SWITCH(F32V)                                                     \
  switch (P) {                                                                \
    case 1:  sumg<F32V, 1 >(Ur, k, hnc, p0, p1, rowf, g0, g1); break;         \
    case 2:  sumg<F32V, 2 >(Ur, k, hnc, p0, p1, rowf, g0, g1); break;         \
    case 3:  sumg<F32V, 3 >(Ur, k, hnc, p0, p1, rowf, g0, g1); break;         \
    case 4:  sumg<F32V, 4 >(Ur, k, hnc, p0, p1, rowf, g0, g1); break;         \
    case 5:  sumg<F32V, 5 >(Ur, k, hnc, p0, p1, rowf, g0, g1); break;         \
    case 6:  sumg<F32V, 6 >(Ur, k, hnc, p0, p1, rowf, g0, g1); break;         \
    case 7:  sumg<F32V, 7 >(Ur, k, hnc, p0, p1, rowf, g0, g1); break;         \
    case 8:  sumg<F32V, 8 >(Ur, k, hnc, p0, p1, rowf, g0, g1); break;         \
    case 9:  sumg<F32V, 9 >(Ur, k, hnc, p0, p1, rowf, g0, g1); break;         \
    case 10: sumg<F32V, 10>(Ur, k, hnc, p0, p1, rowf, g0, g1); break;         \
    case 11: sumg<F32V, 11>(Ur, k, hnc, p0, p1, rowf, g0, g1); break;         \
    case 12: sumg<F32V, 12>(Ur, k, hnc, p0, p1, rowf, g0, g1); break;         \
    case 13: sumg<F32V, 13>(Ur, k, hnc, p0, p1, rowf, g0, g1); break;         \
    case 14: sumg<F32V, 14>(Ur, k, hnc, p0, p1, rowf, g0, g1); break;         \
    case 15: sumg<F32V, 15>(Ur, k, hnc, p0, p1, rowf, g0, g1); break;         \
    case 16: sumg<F32V, 16>(Ur, k, hnc, p0, p1, rowf, g0, g1); break;         \
    default: break;                                                           \
  }

// ---------------------------------------------------------------------------
// Shared neighbor-prep for both gru variants.
// ---------------------------------------------------------------------------
__device__ __forceinline__ int gru_prep(int t, int b0, const int* hni,
                                        int* cid, int* rowf, int* nvs) {
  const int k = threadIdx.x;
  if (k < 2 * MAXNB)
    cid[k] = hni[((long)t * Bb + b0 + (k >> 3)) * MAXNB + (k & 7)];
  __syncthreads();
  if (k == 0) {
    int n0 = 0; while (n0 < MAXNB && cid[n0] != PADID) ++n0;
    int n1 = 0; while (n1 < MAXNB && cid[MAXNB + n1] != PADID) ++n1;
    for (int j = 0; j < n1; ++j) cid[n0 + j] = cid[MAXNB + j];
    for (int p = 0; p < n0 + n1; ++p) rowf[p] = (p >= n0) ? 1 : 0;
    nvs[0] = n0; nvs[1] = n1;
  }
  __syncthreads();
  return nvs[0] + nvs[1];
}

// ---------------------------------------------------------------------------
// GRU scan step, xproj variant: x-projections read from the xproj buffer.
// Per-thread weight loads: Wzh(512) + Ur(512) + Whh(512) + 3 xp.
// ---------------------------------------------------------------------------
template <bool F32>
__device__ void gru_body_xp(int t, const int* wid, const int* hni,
                            const bf16* xproj, const void* Wz, const void* Ur,
                            const void* Wh, bf16* hbuf, float* sh, float* sg,
                            float* hnc, int* cid, int* rowf, int* nvs) {
  const int k = threadIdx.x;
  const int b0 = blockIdx.x * 2;
  const int P = gru_prep(t, b0, hni, cid, rowf, nvs);

  const int w0 = wid[t * Bb + b0];
  const int w1 = wid[t * Bb + b0 + 1];
  const bf16* xp0 = xproj + (long)w0 * XPS;
  const bf16* xp1 = xproj + (long)w1 * XPS;

  float s0 = 0.f, s1 = 0.f;
  for (int p = 0; p < P; ++p) {  // block-uniform bound
    float hv = b2f(hbuf[(long)cid[p] * Hh + k]);
    hnc[p * Hh + k] = hv;
    if (rowf[p]) s1 += hv; else s0 += hv;
  }
  sh[k] = s0; sh[Hh + k] = s1;
  __syncthreads();

  // z pre-activation: xz + sum_h @ Wz[H:]
  float z0 = b2f(xp0[k]), z1 = b2f(xp1[k]);
  for (int i = 0; i < Hh; ++i) {
    float wv = ldv<F32>(Wz, (long)(Hh + i) * Hh + k);
    z0 += sh[i] * wv; z1 += sh[Hh + i] * wv;
  }

  // pre_r from xproj
  float p0 = b2f(xp0[Hh + k]), p1 = b2f(xp1[Hh + k]);

  // sum_g: single Ur stream over all compacted pairs
  float g0 = 0.f, g1 = 0.f;
  SUMG_SWITCH(F32)
  sg[k] = g0; sg[Hh + k] = g1;
  __syncthreads();

  // h_tilde = tanh(xh + sum_g @ Wh[H:])
  float h0 = b2f(xp0[2 * Hh + k]), h1 = b2f(xp1[2 * Hh + k]);
  for (int i = 0; i < Hh; ++i) {
    float wv = ldv<F32>(Wh, (long)(Hh + i) * Hh + k);
    h0 += sg[i] * wv; h1 += sg[Hh + i] * wv;
  }

  float z;
  z = sigm(z0); float o0 = (1.f - z) * s0 + z * tanhf(h0);
  z = sigm(z1); float o1 = (1.f - z) * s1 + z * tanhf(h1);
  hbuf[((long)t * Bb + b0) * Hh + k]     = __float2bfloat16(o0);
  hbuf[((long)t * Bb + b0 + 1) * Hh + k] = __float2bfloat16(o1);
}

__global__ __launch_bounds__(512) void gru_step_xp(
    int t, const int* __restrict__ wid, const int* __restrict__ hni,
    const bf16* xproj, const void* Wz, const void* Ur, const void* Wh,
    bf16* hbuf, const int* __restrict__ flag) {
  __shared__ float sh[2 * Hh];
  __shared__ float sg[2 * Hh];
  __shared__ float hnc[2 * MAXNB * Hh];
  __shared__ int   cid[2 * MAXNB];
  __shared__ int   rowf[2 * MAXNB];
  __shared__ int   nvs[2];
  if (*flag)
    gru_body_xp<true>(t, wid, hni, xproj, Wz, Ur, Wh, hbuf, sh, sg, hnc, cid, rowf, nvs);
  else
    gru_body_xp<false>(t, wid, hni, xproj, Wz, Ur, Wh, hbuf, sh, sg, hnc, cid, rowf, nvs);
}

// ---------------------------------------------------------------------------
// GRU scan step, fallback (no xproj buffer) — R7's proven kernel.
// ---------------------------------------------------------------------------
template <bool F32>
__device__ void gru_body(int t, const int* wid, const int* hni,
                         const void* emb, const void* Wz, const void* bz,
                         const void* Wr, const void* br, const void* Ur,
                         const void* Wh, const void* bh, bf16* hbuf,
                         float* xs, float* sh, float* sg, float* hnc,
                         int* cid, int* rowf, int* nvs) {
  const int k = threadIdx.x;
  const int b0 = blockIdx.x * 2;
  const int P = gru_prep(t, b0, hni, cid, rowf, nvs);

  const int w0 = wid[t * Bb + b0];
  const int w1 = wid[t * Bb + b0 + 1];
  xs[k]      = ldv<F32>(emb, (long)w0 * Hh + k);
  xs[Hh + k] = ldv<F32>(emb, (long)w1 * Hh + k);

  float s0 = 0.f, s1 = 0.f;
  for (int p = 0; p < P; ++p) {
    float hv = b2f(hbuf[(long)cid[p] * Hh + k]);
    hnc[p * Hh + k] = hv;
    if (rowf[p]) s1 += hv; else s0 += hv;
  }
  sh[k] = s0; sh[Hh + k] = s1;
  __syncthreads();

  float bzk = ldv<F32>(bz, k);
  float z0 = bzk, z1 = bzk;
  for (int i = 0; i < Hh; ++i) {
    float wv = ldv<F32>(Wz, (long)i * Hh + k);
    z0 += xs[i] * wv; z1 += xs[Hh + i] * wv;
  }
  for (int i = 0; i < Hh; ++i) {
    float wv = ldv<F32>(Wz, (long)(Hh + i) * Hh + k);
    z0 += sh[i] * wv; z1 += sh[Hh + i] * wv;
  }

  float brk = ldv<F32>(br, k);
  float p0 = brk, p1 = brk;
  for (int i = 0; i < Hh; ++i) {
    float wv = ldv<F32>(Wr, (long)i * Hh + k);
    p0 += xs[i] * wv; p1 += xs[Hh + i] * wv;
  }

  float g0 = 0.f, g1 = 0.f;
  SUMG_SWITCH(F32)
  sg[k] = g0; sg[Hh + k] = g1;
  __syncthreads();

  float bhk = ldv<F32>(bh, k);
  float h0 = bhk, h1 = bhk;
  for (int i = 0; i < Hh; ++i) {
    float wv = ldv<F32>(Wh, (long)i * Hh + k);
    h0 += xs[i] * wv; h1 += xs[Hh + i] * wv;
  }
  for (int i = 0; i < Hh; ++i) {
    float wv = ldv<F32>(Wh, (long)(Hh + i) * Hh + k);
    h0 += sg[i] * wv; h1 += sg[Hh + i] * wv;
  }

  float z;
  z = sigm(z0); float o0 = (1.f - z) * s0 + z * tanhf(h0);
  z = sigm(z1); float o1 = (1.f - z) * s1 + z * tanhf(h1);
  hbuf[((long)t * Bb + b0) * Hh + k]     = __float2bfloat16(o0);
  hbuf[((long)t * Bb + b0 + 1) * Hh + k] = __float2bfloat16(o1);
}

__global__ __launch_bounds__(512) void gru_step(
    int t, const int* __restrict__ wid, const int* __restrict__ hni,
    const void* emb, const void* Wz, const void* bz, const void* Wr,
    const void* br, const void* Ur, const void* Wh, const void* bh,
    bf16* hbuf, const int* __restrict__ flag) {
  __shared__ float xs[2 * Hh];
  __shared__ float sh[2 * Hh];
  __shared__ float sg[2 * Hh];
  __shared__ float hnc[2 * MAXNB * Hh];
  __shared__ int   cid[2 * MAXNB];
  __shared__ int   rowf[2 * MAXNB];
  __shared__ int   nvs[2];
  if (*flag)
    gru_body<true>(t, wid, hni, emb, Wz, bz, Wr, br, Ur, Wh, bh, hbuf,
                   xs, sh, sg, hnc, cid, rowf, nvs);
  else
    gru_body<false>(t, wid, hni, emb, Wz, bz, Wr, br, Ur, Wh, bh, hbuf,
                    xs, sh, sg, hnc, cid, rowf, nvs);
}

// ---------------------------------------------------------------------------
// Stop head: rows = [emb[w] | sum(hbuf[oni]) | mol_vec] (24064 x 1088)
// ---------------------------------------------------------------------------
template <bool F32>
__device__ void stop_body(const void* mol_vec, const int* wid,
                          const int* dirs, const int* oni,
                          const int* root_wid, const int* roni,
                          const void* emb, const void* U, const void* bU,
                          const void* Us, const void* bs, const bf16* hbuf,
                          float* accum,
                          float (*srow)[2 * Hh + Ll], float (*red)[256],
                          float* fin) {
  const int tid = threadIdx.x;
  const int i0 = blockIdx.x * 8;
  const int K = 2 * Hh + Ll;  // 1088

  for (int r = 0; r < 8; ++r) {
    int i = i0 + r;
    int w, b;
    const int* ids;
    if (i < TB) { w = wid[i]; b = i % Bb; ids = &oni[(long)i * MAXNB]; }
    else { int j = i - TB; w = root_wid[j]; b = j; ids = &roni[(long)j * MAXNB]; }
    for (int c = tid; c < K; c += 256) {
      float v;
      if (c < Hh) v = ldv<F32>(emb, (long)w * Hh + c);
      else if (c < 2 * Hh) {
        int cc = c - Hh;
        float s = 0.f;
        for (int j = 0; j < MAXNB; ++j) s += b2f(hbuf[(long)ids[j] * Hh + cc]);
        v = s;
      } else v = ldv<F32>(mol_vec, (long)b * Ll + (c - 2 * Hh));
      srow[r][c] = v;
    }
  }
  __syncthreads();

  const int k0 = tid, k1 = tid + 256;
  float acc[8][2] = {};
  for (int kk = 0; kk < K; ++kk) {
    float u0 = ldv<F32>(U, (long)kk * Hh + k0);
    float u1 = ldv<F32>(U, (long)kk * Hh + k1);
#pragma unroll
    for (int r = 0; r < 8; ++r) {
      float a = srow[r][kk];
      acc[r][0] += a * u0; acc[r][1] += a * u1;
    }
  }
  float bU0 = ldv<F32>(bU, k0), bU1 = ldv<F32>(bU, k1);
  float us0 = ldv<F32>(Us, k0), us1 = ldv<F32>(Us, k1);
  __syncthreads();
#pragma unroll
  for (int r = 0; r < 8; ++r)
    red[r][tid] = fmaxf(acc[r][0] + bU0, 0.f) * us0 + fmaxf(acc[r][1] + bU1, 0.f) * us1;
  __syncthreads();
  for (int off = 128; off; off >>= 1) {
    if (tid < off) {
#pragma unroll
      for (int r = 0; r < 8; ++r) red[r][tid] += red[r][tid + off];
    }
    __syncthreads();
  }
  if (tid < 8) {
    int i = i0 + tid;
    float s = red[tid][0] + ldv<F32>(bs, 0);
    float tgt = (i < TB) ? (float)dirs[i] : 0.f;
    float loss = fmaxf(s, 0.f) - s * tgt + log1pf(expf(-fabsf(s)));
    float ok = ((s >= 0.5f) == (tgt > 0.5f)) ? 1.f : 0.f;
    fin[tid] = loss; fin[8 + tid] = ok;
  }
  __syncthreads();
  if (tid == 0) {
    float ls = 0.f, oks = 0.f;
    for (int r = 0; r < 8; ++r) { ls += fin[r]; oks += fin[8 + r]; }
    atomicAdd(&accum[0], ls);
    atomicAdd(&accum[1], oks);
  }
}

__global__ __launch_bounds__(256) void stop_kernel(
    const void* mol_vec, const int* __restrict__ wid,
    const int* __restrict__ dirs, const int* __restrict__ oni,
    const int* __restrict__ root_wid, const int* __restrict__ roni,
    const void* emb, const void* U, const void* bU, const void* Us,
    const void* bs, const bf16* hbuf, float* accum,
    const int* __restrict__ flag) {
  __shared__ float srow[8][2 * Hh + Ll];
  __shared__ float red[8][256];
  __shared__ float fin[16];
  if (*flag)
    stop_body<true>(mol_vec, wid, dirs, oni, root_wid, roni, emb, U, bU, Us,
                    bs, hbuf, accum, srow, red, fin);
  else
    stop_body<false>(mol_vec, wid, dirs, oni, root_wid, roni, emb, U, bU, Us,
                     bs, hbuf, accum, srow, red, fin);
}

// ---------------------------------------------------------------------------
// Pred head: hid = relu([pred_h | pred_mv] @ W + bW); logits = hid @ Wo + bo
// ---------------------------------------------------------------------------
template <bool F32>
__device__ void pred_body(const void* mol_vec, const int* y_wid,
                          const int* dirs, const int* root_wid, const void* W,
                          const void* bW, const void* Wo, const void* bo,
                          const bf16* hbuf, float* accum,
                          float (*srow)[Hh + Ll], float (*hid)[Hh],
                          float* rv, int* ri, float* sb) {
  const int tid = threadIdx.x;
  const int i0 = blockIdx.x * 8;
  const int K1 = Hh + Ll;  // 576

  for (int r = 0; r < 8; ++r) {
    int i = i0 + r;
    int b = (i < Bb) ? i : (i - Bb) % Bb;
    for (int c = tid; c < K1; c += 256) {
      float v;
      if (c < Hh) v = (i < Bb) ? 0.f : b2f(hbuf[(long)(i - Bb) * Hh + c]);
      else v = ldv<F32>(mol_vec, (long)b * Ll + (c - Hh));
      srow[r][c] = v;
    }
  }
  __syncthreads();

  const int k0 = tid, k1 = tid + 256;
  float acc[8][2] = {};
  for (int kk = 0; kk < K1; ++kk) {
    float w0 = ldv<F32>(W, (long)kk * Hh + k0);
    float w1 = ldv<F32>(W, (long)kk * Hh + k1);
#pragma unroll
    for (int r = 0; r < 8; ++r) {
      float a = srow[r][kk];
      acc[r][0] += a * w0; acc[r][1] += a * w1;
    }
  }
  float bW0 = ldv<F32>(bW, k0), bW1 = ldv<F32>(bW, k1);
#pragma unroll
  for (int r = 0; r < 8; ++r) {
    hid[r][k0] = fmaxf(acc[r][0] + bW0, 0.f);
    hid[r][k1] = fmaxf(acc[r][1] + bW1, 0.f);
  }
  __syncthreads();

  float lg[8][4] = {};
  for (int kk = 0; kk < Hh; ++kk) {
    float w0 = ldv<F32>(Wo, (long)kk * Vv + tid);
    float w1 = ldv<F32>(Wo, (long)kk * Vv + tid + 256);
    float w2 = ldv<F32>(Wo, (long)kk * Vv + tid + 512);
    float w3 = ldv<F32>(Wo, (long)kk * Vv + tid + 768);
#pragma unroll
    for (int r = 0; r < 8; ++r) {
      float a = hid[r][kk];
      lg[r][0] += a * w0; lg[r][1] += a * w1;
      lg[r][2] += a * w2; lg[r][3] += a * w3;
    }
  }
  float bo0 = ldv<F32>(bo, tid);
  float bo1 = ldv<F32>(bo, tid + 256);
  float bo2 = ldv<F32>(bo, tid + 512);
  float bo3 = ldv<F32>(bo, tid + 768);

  float plloss = 0.f, pnum = 0.f, pmask = 0.f;  // live in thread 0
  for (int r = 0; r < 8; ++r) {
    int i = i0 + r;
    int tgt = (i < Bb) ? root_wid[i] : y_wid[i - Bb];
    float msk = (i < Bb) ? 1.f : (float)dirs[i - Bb];
    float v0 = lg[r][0] + bo0, v1 = lg[r][1] + bo1;
    float v2 = lg[r][2] + bo2, v3 = lg[r][3] + bo3;

    float bm = v0; int bi = tid;
    if (v1 > bm) { bm = v1; bi = tid + 256; }
    if (v2 > bm) { bm = v2; bi = tid + 512; }
    if (v3 > bm) { bm = v3; bi = tid + 768; }
    rv[tid] = bm; ri[tid] = bi;
    if ((tgt & 255) == tid) {
      int cc = tgt >> 8;
      sb[0] = (cc == 0) ? v0 : (cc == 1) ? v1 : (cc == 2) ? v2 : v3;
    }
    __syncthreads();
    for (int off = 128; off; off >>= 1) {
      if (tid < off) {
        float o = rv[tid + off]; int oi = ri[tid + off];
        if (o > rv[tid] || (o == rv[tid] && oi < ri[tid])) { rv[tid] = o; ri[tid] = oi; }
      }
      __syncthreads();
    }
    float m = rv[0];
    int am = ri[0];
    __syncthreads();
    rv[tid] = __expf(v0 - m) + __expf(v1 - m) + __expf(v2 - m) + __expf(v3 - m);
    __syncthreads();
    for (int off = 128; off; off >>= 1) {
      if (tid < off) rv[tid] += rv[tid + off];
      __syncthreads();
    }
    if (tid == 0) {
      float lse = m + __logf(rv[0]);
      float ce = lse - sb[0];
      plloss += ce * msk;
      pnum += (am == tgt) ? msk : 0.f;
      pmask += msk;
    }
    __syncthreads();
  }
  if (tid == 0) {
    atomicAdd(&accum[2], plloss);
    atomicAdd(&accum[3], pnum);
    atomicAdd(&accum[4], pmask);
  }
}

__global__ __launch_bounds__(256) void pred_kernel(
    const void* mol_vec, const int* __restrict__ y_wid,
    const int* __restrict__ dirs, const int* __restrict__ root_wid,
    const void* W, const void* bW, const void* Wo, const void* bo,
    const bf16* hbuf, float* accum, const int* __restrict__ flag) {
  __shared__ float srow[8][Hh + Ll];
  __shared__ float hid[8][Hh];
  __shared__ float rv[256];
  __shared__ int   ri[256];
  __shared__ float sb[2];
  if (*flag)
    pred_body<true>(mol_vec, y_wid, dirs, root_wid, W, bW, Wo, bo, hbuf,
                    accum, srow, hid, rv, ri, sb);
  else
    pred_body<false>(mol_vec, y_wid, dirs, root_wid, W, bW, Wo, bo, hbuf,
                     accum, srow, hid, rv, ri, sb);
}

__global__ void finalize_kernel(const float* __restrict__ accum,
                                const int* __restrict__ flag, void* out) {
  if (threadIdx.x == 0 && blockIdx.x == 0) {
    float o0 = accum[2] / (float)Bb;      // pred_loss
    float o1 = accum[0] / (float)Bb;      // stop_loss
    float o2 = accum[3] / accum[4];       // pred_acc
    float o3 = accum[1] / (float)NROWS;   // stop_acc
    if (*flag) {
      float* o = (float*)out;
      o[0] = o0; o[1] = o1; o[2] = o2; o[3] = o3;
    } else {
      bf16* o = (bf16*)out;
      o[0] = __float2bfloat16(o0); o[1] = __float2bfloat16(o1);
      o[2] = __float2bfloat16(o2); o[3] = __float2bfloat16(o3);
    }
  }
}

extern "C" void kernel_launch(void* const* d_in, const int* in_sizes, int n_in,
                              void* d_out, int out_size, void* d_ws, size_t ws_size,
                              hipStream_t stream) {
  const void* mol_vec  = d_in[0];
  const int*  wid      = (const int*)d_in[1];
  const int*  y_wid    = (const int*)d_in[2];
  const int*  dirs     = (const int*)d_in[3];
  const int*  hni      = (const int*)d_in[4];
  const int*  oni      = (const int*)d_in[5];
  const int*  root_wid = (const int*)d_in[6];
  const int*  roni     = (const int*)d_in[7];
  const void* emb      = d_in[8];
  const void* Wz       = d_in[9];
  const void* bz       = d_in[10];
  const void* Wr       = d_in[11];
  const void* br       = d_in[12];
  const void* Ur       = d_in[13];
  const void* Wh       = d_in[14];
  const void* bh       = d_in[15];
  const void* W        = d_in[16];
  const void* bW       = d_in[17];
  const void* U        = d_in[18];
  const void* bU       = d_in[19];
  const void* Wo       = d_in[20];
  const void* bo       = d_in[21];
  const void* Us       = d_in[22];
  const void* bs       = d_in[23];

  // ws layout: [accum 8f][flag 1i][pad->64B][hbuf (TB+1)*Hh bf16][xproj? V*XPS bf16]
  float* accum = (float*)d_ws;
  int*   flag  = (int*)d_ws + 8;
  bf16*  hbuf  = (bf16*)((char*)d_ws + 64);
  bf16*  xproj = hbuf + (long)(TB + 1) * Hh;

  const size_t need_xp = 64 + ((size_t)(TB + 1) * Hh + (size_t)Vv * XPS) * sizeof(bf16);
  const bool use_xp = (ws_size >= need_xp);  // constant across calls: graph-safe

  hipMemsetAsync(d_ws, 0, 64, stream);                                   // accum+flag
  hipMemsetAsync(hbuf + (long)TB * Hh, 0, Hh * sizeof(bf16), stream);    // PAD row

  detect_kernel<<<64, 256, 0, stream>>>((const unsigned short*)emb, flag);

  if (use_xp) {
    xproj_kernel<<<Vv, 512, 0, stream>>>(emb, Wz, bz, Wr, br, Wh, bh, xproj, flag);
    for (int t = 0; t < Tt; ++t) {
      gru_step_xp<<<Bb / 2, 512, 0, stream>>>(t, wid, hni, xproj, Wz, Ur, Wh,
                                              hbuf, flag);
    }
  } else {
    for (int t = 0; t < Tt; ++t) {
      gru_step<<<Bb / 2, 512, 0, stream>>>(t, wid, hni, emb, Wz, bz, Wr, br,
                                           Ur, Wh, bh, hbuf, flag);
    }
  }
  stop_kernel<<<NROWS / 8, 256, 0, stream>>>(mol_vec, wid, dirs, oni, root_wid,
                                             roni, emb, U, bU, Us, bs, hbuf,
                                             accum, flag);
  pred_kernel<<<NROWS / 8, 256, 0, stream>>>(mol_vec, y_wid, dirs, root_wid, W,
                                             bW, Wo, bo, hbuf, accum, flag);
  finalize_kernel<<<1, 64, 0, stream>>>(accum, flag, d_out);
}